// Round 1
// baseline (307.766 us; speedup 1.0000x reference)
//
#include <hip/hip_runtime.h>

// ---------------------------------------------------------------------------
// Fused equivariant NLMP edge kernel, fp32, MI355X.
// Layout: 512 threads/block = 64 edges x 8 threads. Thread j owns output
// column j of every [*,8] weight block. Weights live in LDS transposed to
// [q][16] rows padded to stride 20 (16B aligned, bank-conflict-free).
// ---------------------------------------------------------------------------

#define EPB   64          // edges per block
#define BLOCK (EPB * 8)   // 512 threads

#define SQRT3_F      1.7320508075688772f
#define INV_SQRT3_F  0.5773502691896258f
#define INV_SQRT10_F 0.31622776601683794f
#define A1_4         0.044194173824159216f   // (1/sqrt(32)) * (1/4)
#define A2_4         0.0625f                 // (1/sqrt(16)) * (1/4)

__global__ void zero_f32(float* __restrict__ p, int n) {
    int i = blockIdx.x * blockDim.x + threadIdx.x;
    if (i < n) p[i] = 0.0f;
}

static __device__ __forceinline__ float dot16(const float4 a, const float4 b,
                                              const float4 c, const float4 d,
                                              const float* __restrict__ w) {
    const float4 w0 = *(const float4*)(w + 0);
    const float4 w1 = *(const float4*)(w + 4);
    const float4 w2 = *(const float4*)(w + 8);
    const float4 w3 = *(const float4*)(w + 12);
    return a.x*w0.x + a.y*w0.y + a.z*w0.z + a.w*w0.w
         + b.x*w1.x + b.y*w1.y + b.z*w1.z + b.w*w1.w
         + c.x*w2.x + c.y*w2.y + c.z*w2.z + c.w*w2.w
         + d.x*w3.x + d.y*w3.y + d.z*w3.z + d.w*w3.w;
}

__global__ void __launch_bounds__(BLOCK, 2) eq_nlmp(
    const float* __restrict__ x,        // [N,32]
    const int*   __restrict__ esrc,     // [E]
    const int*   __restrict__ edst,     // [E]
    const float* __restrict__ evec,     // [E,3]
    const float* __restrict__ emb,      // [E,10]
    const float* __restrict__ nrm,      // [E]
    const float* __restrict__ W1,       // [10,16]
    const float* __restrict__ W2,       // [16,512]
    const float* __restrict__ W3,       // [10,16]
    const float* __restrict__ W4,       // [16,384]
    float*       __restrict__ out,      // [N,32]
    int E)
{
    // ---- LDS ----
    __shared__ float sW [512 * 20];   // phase1: W2^T rows [512][20]; phase2: W4^T rows [384][20]
    __shared__ float sW1[160];
    __shared__ float sW3[160];
    __shared__ float sXP[EPB * 68];   // per edge: xs[0..31], xd at +32 (stride 68 = 16B aligned)
    __shared__ float sEM[EPB * 10];   // emb rows
    __shared__ float sSH[EPB * 3];    // sh1 = sqrt(3) * r_hat
    __shared__ float sH [EPB * 20];   // h1 then h2 (stride 20, 16B aligned)
    __shared__ float sST[EPB * 8];    // s_t
    __shared__ float sVT[EPB * 24];   // v_t

    const int tid = threadIdx.x;
    const int e   = tid >> 3;   // local edge 0..63
    const int j   = tid & 7;    // output column 0..7
    int ge        = blockIdx.x * EPB + e;
    const bool act = (ge < E);
    if (!act) ge = E - 1;       // clamp; loads harmless, stores guarded

    // ---- stage phase-1 weights: sW[q*20+h] = W2[h][q] ----
    for (int idx = tid; idx < 8192; idx += BLOCK) {
        int h = idx >> 9, q = idx & 511;
        sW[q * 20 + h] = W2[idx];
    }
    if (tid < 160) { sW1[tid] = W1[tid]; sW3[tid] = W3[tid]; }

    // ---- per-edge data loads ----
    const int src = esrc[ge];
    const int dst = edst[ge];
    {
        const float4* xs4 = (const float4*)(x + (size_t)src * 32);
        const float4* xd4 = (const float4*)(x + (size_t)dst * 32);
        float4 a = xs4[j];
        float4 b = xd4[j];
        *(float4*)&sXP[e * 68 + 4 * j]      = a;
        *(float4*)&sXP[e * 68 + 32 + 4 * j] = b;
    }
    if (j < 5) {
        float2 t = *(const float2*)(emb + (size_t)ge * 10 + 2 * j);
        *(float2*)&sEM[e * 10 + 2 * j] = t;
    }
    if (j == 0) {
        float vx = evec[(size_t)ge * 3 + 0];
        float vy = evec[(size_t)ge * 3 + 1];
        float vz = evec[(size_t)ge * 3 + 2];
        float rn = sqrtf(vx * vx + vy * vy + vz * vz);
        sSH[e * 3 + 0] = SQRT3_F * vx / rn;
        sSH[e * 3 + 1] = SQRT3_F * vy / rn;
        sSH[e * 3 + 2] = SQRT3_F * vz / rn;
    }
    __syncthreads();

    // ---- h1 = relu(emb @ W1 / sqrt(10)) : each thread computes h[j], h[j+8] ----
    #pragma unroll
    for (int t = 0; t < 2; ++t) {
        const int hid = j + 8 * t;
        float acc = 0.0f;
        #pragma unroll
        for (int i = 0; i < 10; ++i) acc += sEM[e * 10 + i] * sW1[i * 16 + hid];
        sH[e * 20 + hid] = fmaxf(acc * INV_SQRT10_F, 0.0f);
    }
    __syncthreads();

    const float sh0 = sSH[e * 3 + 0], sh1 = sSH[e * 3 + 1], sh2 = sSH[e * 3 + 2];

    // ---- TP1: stream w = h1 @ W2 (never materialized), contract over u=0..15 ----
    float sts = 0.0f, svs = 0.0f, vt0 = 0.0f, vt1 = 0.0f, vt2 = 0.0f;
    {
        const float4 ha = *(const float4*)&sH[e * 20 + 0];
        const float4 hb = *(const float4*)&sH[e * 20 + 4];
        const float4 hc = *(const float4*)&sH[e * 20 + 8];
        const float4 hd = *(const float4*)&sH[e * 20 + 12];
        for (int u = 0; u < 16; ++u) {
            const int so = (u < 8) ? u : (u + 24);
            const int vo = (u < 8) ? (8 + 3 * u) : (16 + 3 * u);
            const float su = sXP[e * 68 + so];
            const float a0 = sXP[e * 68 + vo + 0];
            const float a1 = sXP[e * 68 + vo + 1];
            const float a2 = sXP[e * 68 + vo + 2];
            const float vd = (a0 * sh0 + a1 * sh1 + a2 * sh2) * INV_SQRT3_F;
            const float* wb = &sW[(u * 8 + j) * 20];
            const float wss = dot16(ha, hb, hc, hd, wb);
            const float wvv = dot16(ha, hb, hc, hd, wb + 128 * 20);
            const float wsv = dot16(ha, hb, hc, hd, wb + 256 * 20);
            const float wvs = dot16(ha, hb, hc, hd, wb + 384 * 20);
            sts += su * wss + vd * wvv;
            svs += su * wsv;
            vt0 += a0 * wvs;
            vt1 += a1 * wvs;
            vt2 += a2 * wvs;
        }
    }
    // s_t, v_t (both carry a1 * 1/4)
    sST[e * 8 + j] = sts * A1_4;
    const float vtx = (svs * sh0 + vt0) * A1_4;
    const float vty = (svs * sh1 + vt1) * A1_4;
    const float vtz = (svs * sh2 + vt2) * A1_4;
    sVT[e * 24 + 3 * j + 0] = vtx;
    sVT[e * 24 + 3 * j + 1] = vty;
    sVT[e * 24 + 3 * j + 2] = vtz;
    __syncthreads();

    // ---- stage phase-2 weights: sW[q*20+h] = W4[h][q]; and h2 from W3 ----
    #pragma unroll 4
    for (int h = 0; h < 16; ++h) {
        if (tid < 384) sW[tid * 20 + h] = W4[h * 384 + tid];
    }
    #pragma unroll
    for (int t = 0; t < 2; ++t) {
        const int hid = j + 8 * t;
        float acc = 0.0f;
        #pragma unroll
        for (int i = 0; i < 10; ++i) acc += sEM[e * 10 + i] * sW3[i * 16 + hid];
        sH[e * 20 + hid] = fmaxf(acc * INV_SQRT10_F, 0.0f);
    }
    __syncthreads();

    // ---- TP2: contract over u=0..7 ----
    float scal = 0.0f, gat = 0.0f, csv = 0.0f, vv0 = 0.0f, vv1 = 0.0f, vv2 = 0.0f;
    {
        const float4 ha = *(const float4*)&sH[e * 20 + 0];
        const float4 hb = *(const float4*)&sH[e * 20 + 4];
        const float4 hc = *(const float4*)&sH[e * 20 + 8];
        const float4 hd = *(const float4*)&sH[e * 20 + 12];
        for (int u = 0; u < 8; ++u) {
            const float su = sST[e * 8 + u];
            const float b0 = sVT[e * 24 + 3 * u + 0];
            const float b1 = sVT[e * 24 + 3 * u + 1];
            const float b2 = sVT[e * 24 + 3 * u + 2];
            const float vd = (b0 * sh0 + b1 * sh1 + b2 * sh2) * INV_SQRT3_F;
            const float* wb = &sW[(u * 8 + j) * 20];
            const float wA  = dot16(ha, hb, hc, hd, wb);             // Ass
            const float wAv = dot16(ha, hb, hc, hd, wb +  64 * 20);  // Avv
            const float wB  = dot16(ha, hb, hc, hd, wb + 128 * 20);  // Bss
            const float wBv = dot16(ha, hb, hc, hd, wb + 192 * 20);  // Bvv
            const float wC  = dot16(ha, hb, hc, hd, wb + 256 * 20);  // Csv
            const float wCv = dot16(ha, hb, hc, hd, wb + 320 * 20);  // Cvs
            scal += su * wA + vd * wAv;
            gat  += su * wB + vd * wBv;
            csv  += su * wC;
            vv0  += b0 * wCv;
            vv1  += b1 * wCv;
            vv2  += b2 * wCv;
        }
    }
    scal *= A2_4;
    gat  *= A2_4;
    const float ve0 = (csv * sh0 + vv0) * A2_4;
    const float ve1 = (csv * sh1 + vv1) * A2_4;
    const float ve2 = (csv * sh2 + vv2) * A2_4;

    const float ts = tanhf(scal);
    const float tg = tanhf(gat);
    const float nn = nrm[ge];

    if (act) {
        float* ob = out + (size_t)dst * 32;
        atomicAdd(ob + j,             ts  * nn);
        atomicAdd(ob + 8 + 3 * j + 0, ve0 * tg * nn);
        atomicAdd(ob + 8 + 3 * j + 1, ve1 * tg * nn);
        atomicAdd(ob + 8 + 3 * j + 2, ve2 * tg * nn);
    }
}

extern "C" void kernel_launch(void* const* d_in, const int* in_sizes, int n_in,
                              void* d_out, int out_size, void* d_ws, size_t ws_size,
                              hipStream_t stream) {
    const float* x    = (const float*)d_in[0];
    const int*   esrc = (const int*)  d_in[1];
    const int*   edst = (const int*)  d_in[2];
    const float* evec = (const float*)d_in[3];
    const float* emb  = (const float*)d_in[4];
    const float* nrm  = (const float*)d_in[5];
    // d_in[6] = num_nodes (scalar) — implied by out_size
    const float* W1   = (const float*)d_in[7];
    const float* W2   = (const float*)d_in[8];
    const float* W3   = (const float*)d_in[9];
    const float* W4   = (const float*)d_in[10];
    float* out = (float*)d_out;

    const int E = in_sizes[1];  // edge_src count

    zero_f32<<<(out_size + 255) / 256, 256, 0, stream>>>(out, out_size);

    const int grid = (E + EPB - 1) / EPB;
    eq_nlmp<<<grid, BLOCK, 0, stream>>>(x, esrc, edst, evec, emb, nrm,
                                        W1, W2, W3, W4, out, E);
}